// Round 1
// baseline (442.685 us; speedup 1.0000x reference)
//
#include <hip/hip_runtime.h>
#include <hip/hip_bf16.h>
#include <math.h>

#define OBS_DIM 256
#define FEAT 128
#define HID 64
#define N_OPT 8
#define ACT_N 18
#define BATCH 32768

// workspace layout
#define STATE_BYTES ((size_t)BATCH * FEAT * sizeof(float))   // 16 MiB
#define CNT_OFF STATE_BYTES
#define IDX_OFF (STATE_BYTES + 256)

// ---------------------------------------------------------------------------
// K1: bucket rows by option. LDS sub-histogram, one global atomic per option
// per block (guideline 12), then scatter row indices.
// ---------------------------------------------------------------------------
__global__ __launch_bounds__(256) void k_bucket(const int* __restrict__ opt,
                                                int* __restrict__ cnt,
                                                int* __restrict__ idx) {
    __shared__ int lcnt[N_OPT];
    __shared__ int lbase[N_OPT];
    int tid = threadIdx.x;
    if (tid < N_OPT) lcnt[tid] = 0;
    __syncthreads();
    int row = blockIdx.x * 256 + tid;
    int o = opt[row];
    int lpos = atomicAdd(&lcnt[o], 1);
    __syncthreads();
    if (tid < N_OPT) lbase[tid] = atomicAdd(&cnt[tid], lcnt[tid]);
    __syncthreads();
    idx[o * BATCH + lbase[o] + lpos] = row;
}

// ---------------------------------------------------------------------------
// K2: feature trunk + option-value / termination heads.
// One thread per row. h[64] lives in registers (fully unrolled indexing).
// state[j2] is produced one at a time: stored to ws and folded into the two
// head dot-products, so no 128-wide register array is needed.
// Weight addresses are wave-uniform -> scalar loads.
// ---------------------------------------------------------------------------
__global__ __launch_bounds__(64) void k_trunk(
    const float* __restrict__ obs, const int* __restrict__ opt,
    const float* __restrict__ fW1, const float* __restrict__ fb1,
    const float* __restrict__ fW2, const float* __restrict__ fb2,
    const float* __restrict__ pW,  const float* __restrict__ pb,
    const float* __restrict__ tW,  const float* __restrict__ tb,
    float* __restrict__ state, float* __restrict__ out)
{
    int row = blockIdx.x * 64 + threadIdx.x;

    // ---- layer 1: h = relu(obs @ fW1^T + fb1) ----
    float h[HID];
#pragma unroll
    for (int j = 0; j < HID; ++j) h[j] = fb1[j];

    const float4* op4 = reinterpret_cast<const float4*>(obs + (size_t)row * OBS_DIM);
    for (int k4 = 0; k4 < OBS_DIM / 4; ++k4) {
        float4 ov = op4[k4];
#pragma unroll
        for (int j = 0; j < HID; ++j) {
            const float* w = &fW1[j * OBS_DIM + k4 * 4];
            float a = fmaf(ov.x, w[0], h[j]);
            a = fmaf(ov.y, w[1], a);
            a = fmaf(ov.z, w[2], a);
            a = fmaf(ov.w, w[3], a);
            h[j] = a;
        }
    }
#pragma unroll
    for (int j = 0; j < HID; ++j) h[j] = fmaxf(h[j], 0.f);

    // ---- layer 2 + heads, streaming over j2 ----
    int o = opt[row];
    float pv = pb[o];
    float tv = tb[o];
    float* srow = state + (size_t)row * FEAT;

    for (int j2b = 0; j2b < FEAT; j2b += 4) {
        float4 sv;
        float* svp = &sv.x;
#pragma unroll
        for (int q = 0; q < 4; ++q) {
            int j2 = j2b + q;
            const float* w = &fW2[j2 * HID];
            float s0 = 0.f, s1 = 0.f, s2 = 0.f, s3 = 0.f;
#pragma unroll
            for (int j = 0; j < HID; j += 4) {
                s0 = fmaf(h[j + 0], w[j + 0], s0);
                s1 = fmaf(h[j + 1], w[j + 1], s1);
                s2 = fmaf(h[j + 2], w[j + 2], s2);
                s3 = fmaf(h[j + 3], w[j + 3], s3);
            }
            float s = fb2[j2] + ((s0 + s1) + (s2 + s3));
            s = fmaxf(s, 0.f);
            svp[q] = s;
            pv = fmaf(s, pW[o * FEAT + j2], pv);
            tv = fmaf(s, tW[o * FEAT + j2], tv);
        }
        *reinterpret_cast<float4*>(srow + j2b) = sv;
    }

    out[BATCH + row] = pv;                       // optval
    out[2 * BATCH + row] = 1.f / (1.f + expf(-tv));  // termprob
}

// ---------------------------------------------------------------------------
// K3: per-option expert MLP + log-softmax(act).
// Blocks are option-uniform (via K1 buckets) so expert weight addresses are
// wave-uniform -> scalar loads. state row held in 128 registers.
// ---------------------------------------------------------------------------
__global__ __launch_bounds__(256) void k_expert(
    const float* __restrict__ state, const int* __restrict__ cnt,
    const int* __restrict__ idx, const int* __restrict__ act,
    const float* __restrict__ oW1, const float* __restrict__ ob1,
    const float* __restrict__ oW2, const float* __restrict__ ob2,
    float* __restrict__ out)
{
    int o = blockIdx.x & 7;
    int chunk = blockIdx.x >> 3;         // 0..63
    int n = cnt[o];
    const float* W1 = oW1 + (size_t)o * HID * FEAT;
    const float* W2 = oW2 + (size_t)o * ACT_N * HID;
    const float* b1 = ob1 + o * HID;
    const float* b2 = ob2 + o * ACT_N;

    for (int i = chunk * 256 + (int)threadIdx.x; i < n; i += 64 * 256) {
        int row = idx[o * BATCH + i];

        float st[FEAT];
        const float4* sp = reinterpret_cast<const float4*>(state + (size_t)row * FEAT);
#pragma unroll
        for (int k4 = 0; k4 < FEAT / 4; ++k4) {
            float4 v = sp[k4];
            st[4 * k4 + 0] = v.x; st[4 * k4 + 1] = v.y;
            st[4 * k4 + 2] = v.z; st[4 * k4 + 3] = v.w;
        }

        float logits[ACT_N];
#pragma unroll
        for (int a = 0; a < ACT_N; ++a) logits[a] = b2[a];

        for (int e = 0; e < HID; ++e) {
            const float* w = &W1[e * FEAT];
            float a0 = 0.f, a1 = 0.f, a2 = 0.f, a3 = 0.f;
#pragma unroll
            for (int k = 0; k < FEAT; k += 4) {
                a0 = fmaf(st[k + 0], w[k + 0], a0);
                a1 = fmaf(st[k + 1], w[k + 1], a1);
                a2 = fmaf(st[k + 2], w[k + 2], a2);
                a3 = fmaf(st[k + 3], w[k + 3], a3);
            }
            float eh = b1[e] + ((a0 + a1) + (a2 + a3));
            eh = fmaxf(eh, 0.f);
#pragma unroll
            for (int a = 0; a < ACT_N; ++a)
                logits[a] = fmaf(eh, W2[a * HID + e], logits[a]);
        }

        float mx = logits[0];
#pragma unroll
        for (int a = 1; a < ACT_N; ++a) mx = fmaxf(mx, logits[a]);
        float ssum = 0.f;
#pragma unroll
        for (int a = 0; a < ACT_N; ++a) ssum += expf(logits[a] - mx);
        int aa = act[row];
        out[row] = (logits[aa] - mx) - logf(ssum);
    }
}

// ---------------------------------------------------------------------------
extern "C" void kernel_launch(void* const* d_in, const int* in_sizes, int n_in,
                              void* d_out, int out_size, void* d_ws, size_t ws_size,
                              hipStream_t stream) {
    const float* obs = (const float*)d_in[0];
    const int*   act = (const int*)d_in[1];
    const int*   opt = (const int*)d_in[2];
    const float* fW1 = (const float*)d_in[3];
    const float* fb1 = (const float*)d_in[4];
    const float* fW2 = (const float*)d_in[5];
    const float* fb2 = (const float*)d_in[6];
    const float* pW  = (const float*)d_in[7];
    const float* pb  = (const float*)d_in[8];
    const float* tW  = (const float*)d_in[9];
    const float* tb  = (const float*)d_in[10];
    const float* oW1 = (const float*)d_in[11];
    const float* ob1 = (const float*)d_in[12];
    const float* oW2 = (const float*)d_in[13];
    const float* ob2 = (const float*)d_in[14];
    float* out = (float*)d_out;

    float* state = (float*)d_ws;
    int* cnt = (int*)((char*)d_ws + CNT_OFF);
    int* idx = (int*)((char*)d_ws + IDX_OFF);

    hipMemsetAsync(cnt, 0, N_OPT * sizeof(int), stream);
    k_bucket<<<BATCH / 256, 256, 0, stream>>>(opt, cnt, idx);
    k_trunk<<<BATCH / 64, 64, 0, stream>>>(obs, opt, fW1, fb1, fW2, fb2,
                                           pW, pb, tW, tb, state, out);
    k_expert<<<512, 256, 0, stream>>>(state, cnt, idx, act, oW1, ob1, oW2, ob2, out);
}

// Round 2
// 134.606 us; speedup vs baseline: 3.2887x; 3.2887x over previous
//
#include <hip/hip_runtime.h>
#include <hip/hip_bf16.h>
#include <math.h>

#define OBS_DIM 256
#define FEAT 128
#define HID 64
#define N_OPT 8
#define ACT_N 18
#define BATCH 32768

typedef unsigned short u16;
typedef unsigned int u32;
typedef __attribute__((ext_vector_type(8))) short short8;
typedef __attribute__((ext_vector_type(4))) float f32x4;
typedef __attribute__((ext_vector_type(4))) u16 u16x4;

#define MFMA(a, b, c) __builtin_amdgcn_mfma_f32_16x16x32_bf16((a), (b), (c), 0, 0, 0)

// XOR swizzle (T2): flips byte bits 4..6 by row&7 — keeps ds_read_b128 A-frags
// (16 lanes, 16 rows, same col) spread over 8 distinct 16B slots -> <=2-way.
#define SWZ(row, off) ((off) ^ (((row) & 7) << 4))

// ---- ws layout (bytes) ----
#define WS_STATE   0                         // bf16 [BATCH][128]  8 MiB
#define WS_FW1     (8388608)                 // bf16 [64][256]
#define WS_FW2     (WS_FW1 + 64*256*2)       // bf16 [128][64]
#define WS_PW      (WS_FW2 + 128*64*2)       // bf16 [16][128] zero-padded
#define WS_TW      (WS_PW  + 16*128*2)       // bf16 [16][128] zero-padded
#define WS_OW1     (WS_TW  + 16*128*2)       // bf16 [8][64][128]
#define WS_OW2     (WS_OW1 + 8*64*128*2)     // bf16 [8][32][64] zero-padded
#define WS_CNT     (WS_OW2 + 8*32*64*2)      // int [8] (pad 128B)
#define WS_IDX     (WS_CNT + 128)            // int [8][BATCH]

__device__ __forceinline__ u16 bf(float x) {  // RNE f32->bf16
    u32 u = __float_as_uint(x);
    return (u16)((u + 0x7fffu + ((u >> 16) & 1u)) >> 16);
}

// ---------------------------------------------------------------------------
// K0: weight conversion fp32 -> bf16 (+ zero padding)
// ---------------------------------------------------------------------------
__global__ __launch_bounds__(256) void k_prep(
    const float* __restrict__ fW1, const float* __restrict__ fW2,
    const float* __restrict__ pW,  const float* __restrict__ tW,
    const float* __restrict__ oW1, const float* __restrict__ oW2,
    u16* __restrict__ fW1b, u16* __restrict__ fW2b,
    u16* __restrict__ pWb,  u16* __restrict__ tWb,
    u16* __restrict__ oW1b, u16* __restrict__ oW2b)
{
    int gid = blockIdx.x * 256 + threadIdx.x;
    int stride = gridDim.x * 256;
    for (int i = gid; i < 64 * 256; i += stride) fW1b[i] = bf(fW1[i]);
    for (int i = gid; i < 128 * 64; i += stride) fW2b[i] = bf(fW2[i]);
    for (int i = gid; i < 16 * 128; i += stride) {
        int r = i >> 7;
        pWb[i] = (r < 8) ? bf(pW[i]) : (u16)0;
        tWb[i] = (r < 8) ? bf(tW[i]) : (u16)0;
    }
    for (int i = gid; i < 8 * 64 * 128; i += stride) oW1b[i] = bf(oW1[i]);
    for (int i = gid; i < 8 * 32 * 64; i += stride) {
        int o = i >> 11, a = (i >> 6) & 31, e = i & 63;
        oW2b[i] = (a < ACT_N) ? bf(oW2[(o * ACT_N + a) * 64 + e]) : (u16)0;
    }
}

// ---------------------------------------------------------------------------
// K1: bucket rows by option (unchanged from round 0 — verified)
// ---------------------------------------------------------------------------
__global__ __launch_bounds__(256) void k_bucket(const int* __restrict__ opt,
                                                int* __restrict__ cnt,
                                                int* __restrict__ idx) {
    __shared__ int lcnt[N_OPT];
    __shared__ int lbase[N_OPT];
    int tid = threadIdx.x;
    if (tid < N_OPT) lcnt[tid] = 0;
    __syncthreads();
    int row = blockIdx.x * 256 + tid;
    int o = opt[row];
    int lpos = atomicAdd(&lcnt[o], 1);
    __syncthreads();
    if (tid < N_OPT) lbase[tid] = atomicAdd(&cnt[tid], lcnt[tid]);
    __syncthreads();
    idx[o * BATCH + lbase[o] + lpos] = row;
}

// ---------------------------------------------------------------------------
// K2: trunk via MFMA. 64 rows/block, 4 waves (each owns a 16-row band).
// layer1: [64,256]@[256,64] (8 K-steps x 4 N-frags)
// layer2: [64,64]@[64,128]  (2 K-steps x 8 N-frags)
// heads:  [64,128]@[128,16(pad 8)] x2, select col=opt via shfl.
// ---------------------------------------------------------------------------
__global__ __launch_bounds__(256) void k_trunk(
    const float* __restrict__ obs, const int* __restrict__ opt,
    const u16* __restrict__ fW1b, const float* __restrict__ fb1,
    const u16* __restrict__ fW2b, const float* __restrict__ fb2,
    const u16* __restrict__ pWb,  const float* __restrict__ pb,
    const u16* __restrict__ tWb,  const float* __restrict__ tb,
    u16* __restrict__ state_g, float* __restrict__ out)
{
    __shared__ u16 lA[64 * 256];  // obs tile bf16 (swizzled)  32 KiB
    __shared__ u16 lH[64 * 64];   // h (swizzled)               8 KiB
    __shared__ u16 lS[64 * 128];  // state (swizzled)          16 KiB

    const int tid = threadIdx.x;
    const int tile = blockIdx.x;
    const int w = tid >> 6, l = tid & 63, lg = l >> 4, lc = l & 15;

    // ---- stage obs: wave-contiguous loads; each float4 is 4 cols of one row
    const float* op = obs + (size_t)tile * 64 * OBS_DIM;
    {
        char* lab = (char*)lA;
#pragma unroll
        for (int i = 0; i < 16; ++i) {
            int flat = tid * 4 + i * 1024;
            float4 v = *reinterpret_cast<const float4*>(op + flat);
            int row = flat >> 8, col = flat & 255;
            u16x4 u;
            u.x = bf(v.x); u.y = bf(v.y); u.z = bf(v.z); u.w = bf(v.w);
            *reinterpret_cast<u16x4*>(lab + row * 512 + SWZ(row, col * 2)) = u;
        }
    }
    __syncthreads();

    // ---- layer 1 ----
    f32x4 acc1[4] = {{0.f,0.f,0.f,0.f},{0.f,0.f,0.f,0.f},{0.f,0.f,0.f,0.f},{0.f,0.f,0.f,0.f}};
    {
        const int arow = 16 * w + lc;
        const char* lab = (const char*)lA;
#pragma unroll
        for (int ks = 0; ks < 8; ++ks) {
            short8 a = *reinterpret_cast<const short8*>(lab + arow * 512 + SWZ(arow, ks * 64 + lg * 16));
#pragma unroll
            for (int nn = 0; nn < 4; ++nn) {
                short8 b = *reinterpret_cast<const short8*>(fW1b + (nn * 16 + lc) * 256 + ks * 32 + lg * 8);
                acc1[nn] = MFMA(a, b, acc1[nn]);
            }
        }
    }
#pragma unroll
    for (int nn = 0; nn < 4; ++nn) {
        int col = nn * 16 + lc;
        float bias = fb1[col];
#pragma unroll
        for (int r = 0; r < 4; ++r) {
            int row = 16 * w + 4 * lg + r;
            *(u16*)((char*)lH + row * 128 + SWZ(row, col * 2)) = bf(fmaxf(acc1[nn][r] + bias, 0.f));
        }
    }
    __syncthreads();

    // ---- layer 2 ----
    f32x4 acc2[8];
#pragma unroll
    for (int nn = 0; nn < 8; ++nn) acc2[nn] = (f32x4){0.f,0.f,0.f,0.f};
    {
        const int arow = 16 * w + lc;
        const char* lhb = (const char*)lH;
#pragma unroll
        for (int ks = 0; ks < 2; ++ks) {
            short8 a = *reinterpret_cast<const short8*>(lhb + arow * 128 + SWZ(arow, ks * 64 + lg * 16));
#pragma unroll
            for (int nn = 0; nn < 8; ++nn) {
                short8 b = *reinterpret_cast<const short8*>(fW2b + (nn * 16 + lc) * 64 + ks * 32 + lg * 8);
                acc2[nn] = MFMA(a, b, acc2[nn]);
            }
        }
    }
#pragma unroll
    for (int nn = 0; nn < 8; ++nn) {
        int col = nn * 16 + lc;
        float bias = fb2[col];
#pragma unroll
        for (int r = 0; r < 4; ++r) {
            int row = 16 * w + 4 * lg + r;
            *(u16*)((char*)lS + row * 256 + SWZ(row, col * 2)) = bf(fmaxf(acc2[nn][r] + bias, 0.f));
        }
    }
    __syncthreads();

    // ---- state -> global (linear, coalesced) ----
    {
        int row = tid >> 2, q = tid & 3;
        char* dst = (char*)(state_g + ((size_t)tile * 64 + row) * FEAT);
#pragma unroll
        for (int u = 0; u < 4; ++u) {
            short8 v = *reinterpret_cast<const short8*>((char*)lS + row * 256 + SWZ(row, q * 64 + u * 16));
            *reinterpret_cast<short8*>(dst + q * 64 + u * 16) = v;
        }
    }

    // ---- heads ----
    f32x4 accP = {0.f,0.f,0.f,0.f}, accT = {0.f,0.f,0.f,0.f};
    {
        const int arow = 16 * w + lc;
        const char* lsb = (const char*)lS;
#pragma unroll
        for (int ks = 0; ks < 4; ++ks) {
            short8 a = *reinterpret_cast<const short8*>(lsb + arow * 256 + SWZ(arow, ks * 64 + lg * 16));
            short8 bp = *reinterpret_cast<const short8*>(pWb + lc * 128 + ks * 32 + lg * 8);
            short8 bt = *reinterpret_cast<const short8*>(tWb + lc * 128 + ks * 32 + lg * 8);
            accP = MFMA(a, bp, accP);
            accT = MFMA(a, bt, accT);
        }
    }
#pragma unroll
    for (int r = 0; r < 4; ++r) {
        int row = 16 * w + 4 * lg + r;
        int grow = tile * 64 + row;
        int o = opt[grow];
        float pv = __shfl(accP[r], (l & 48) | o, 64);
        float tv = __shfl(accT[r], (l & 48) | o, 64);
        if (lc == 0) {
            out[BATCH + grow] = pv + pb[o];
            out[2 * BATCH + grow] = 1.f / (1.f + expf(-(tv + tb[o])));
        }
    }
}

// ---------------------------------------------------------------------------
// K3: expert MLP, option-uniform 64-row tiles.
// layer1: [64,128]@[128,64] (4 K x 4 N); layer2: [64,64]@[64,32pad] (2 K x 2 N)
// then 18-wide log-softmax per row from LDS.
// ---------------------------------------------------------------------------
__global__ __launch_bounds__(256) void k_expert(
    const u16* __restrict__ state_g, const int* __restrict__ cnt,
    const int* __restrict__ idx, const int* __restrict__ act,
    const u16* __restrict__ oW1b, const float* __restrict__ ob1,
    const u16* __restrict__ oW2b, const float* __restrict__ ob2,
    float* __restrict__ out)
{
    __shared__ u16 lS[64 * 128];  // gathered state (swizzled) 16 KiB
    __shared__ u16 lE[64 * 64];   // expert hidden (swizzled)   8 KiB
    __shared__ float lL[64 * 19]; // logits                     4.75 KiB

    const int tid = threadIdx.x;
    const int o = blockIdx.x & 7, c0 = blockIdx.x >> 3;
    const int n = cnt[o];
    const int ntiles = (n + 63) >> 6;
    const u16* W1 = oW1b + o * HID * FEAT;
    const u16* W2 = oW2b + o * 32 * HID;
    const float* b1 = ob1 + o * HID;
    const float* b2 = ob2 + o * ACT_N;
    const int w = tid >> 6, l = tid & 63, lg = l >> 4, lc = l & 15;

    for (int t = c0; t < ntiles; t += 64) {
        // ---- gather state rows into LDS ----
        {
            int lrow = tid >> 2, q = tid & 3;
            int i = t * 64 + lrow;
            int grow = (i < n) ? idx[o * BATCH + i] : -1;
#pragma unroll
            for (int u = 0; u < 4; ++u) {
                short8 v;
                if (grow >= 0)
                    v = *reinterpret_cast<const short8*>((const char*)(state_g + (size_t)grow * FEAT) + q * 64 + u * 16);
                else
                    v = (short8)0;
                *reinterpret_cast<short8*>((char*)lS + lrow * 256 + SWZ(lrow, q * 64 + u * 16)) = v;
            }
        }
        __syncthreads();

        // ---- layer 1 ----
        f32x4 acc[4];
#pragma unroll
        for (int nn = 0; nn < 4; ++nn) acc[nn] = (f32x4){0.f,0.f,0.f,0.f};
        {
            const int arow = 16 * w + lc;
            const char* lsb = (const char*)lS;
#pragma unroll
            for (int ks = 0; ks < 4; ++ks) {
                short8 a = *reinterpret_cast<const short8*>(lsb + arow * 256 + SWZ(arow, ks * 64 + lg * 16));
#pragma unroll
                for (int nn = 0; nn < 4; ++nn) {
                    short8 b = *reinterpret_cast<const short8*>(W1 + (nn * 16 + lc) * 128 + ks * 32 + lg * 8);
                    acc[nn] = MFMA(a, b, acc[nn]);
                }
            }
        }
#pragma unroll
        for (int nn = 0; nn < 4; ++nn) {
            int col = nn * 16 + lc;
            float bias = b1[col];
#pragma unroll
            for (int r = 0; r < 4; ++r) {
                int row = 16 * w + 4 * lg + r;
                *(u16*)((char*)lE + row * 128 + SWZ(row, col * 2)) = bf(fmaxf(acc[nn][r] + bias, 0.f));
            }
        }
        __syncthreads();

        // ---- layer 2 ----
        f32x4 acc2[2];
        acc2[0] = (f32x4){0.f,0.f,0.f,0.f};
        acc2[1] = (f32x4){0.f,0.f,0.f,0.f};
        {
            const int arow = 16 * w + lc;
            const char* leb = (const char*)lE;
#pragma unroll
            for (int ks = 0; ks < 2; ++ks) {
                short8 a = *reinterpret_cast<const short8*>(leb + arow * 128 + SWZ(arow, ks * 64 + lg * 16));
#pragma unroll
                for (int nn = 0; nn < 2; ++nn) {
                    short8 b = *reinterpret_cast<const short8*>(W2 + (nn * 16 + lc) * 64 + ks * 32 + lg * 8);
                    acc2[nn] = MFMA(a, b, acc2[nn]);
                }
            }
        }
#pragma unroll
        for (int nn = 0; nn < 2; ++nn) {
            int col = nn * 16 + lc;
            if (col < ACT_N) {
                float bias = b2[col];
#pragma unroll
                for (int r = 0; r < 4; ++r) {
                    int row = 16 * w + 4 * lg + r;
                    lL[row * 19 + col] = acc2[nn][r] + bias;
                }
            }
        }
        __syncthreads();

        // ---- log-softmax + gather(act) ----
        if (tid < 64) {
            int i = t * 64 + tid;
            if (i < n) {
                int grow = idx[o * BATCH + i];
                const float* lr = &lL[tid * 19];
                float mx = lr[0];
#pragma unroll
                for (int a = 1; a < ACT_N; ++a) mx = fmaxf(mx, lr[a]);
                float s = 0.f;
#pragma unroll
                for (int a = 0; a < ACT_N; ++a) s += expf(lr[a] - mx);
                int aa = act[grow];
                out[grow] = (lr[aa] - mx) - logf(s);
            }
        }
        __syncthreads();
    }
}

// ---------------------------------------------------------------------------
extern "C" void kernel_launch(void* const* d_in, const int* in_sizes, int n_in,
                              void* d_out, int out_size, void* d_ws, size_t ws_size,
                              hipStream_t stream) {
    const float* obs = (const float*)d_in[0];
    const int*   act = (const int*)d_in[1];
    const int*   opt = (const int*)d_in[2];
    const float* fW1 = (const float*)d_in[3];
    const float* fb1 = (const float*)d_in[4];
    const float* fW2 = (const float*)d_in[5];
    const float* fb2 = (const float*)d_in[6];
    const float* pW  = (const float*)d_in[7];
    const float* pb  = (const float*)d_in[8];
    const float* tW  = (const float*)d_in[9];
    const float* tb  = (const float*)d_in[10];
    const float* oW1 = (const float*)d_in[11];
    const float* ob1 = (const float*)d_in[12];
    const float* oW2 = (const float*)d_in[13];
    const float* ob2 = (const float*)d_in[14];
    float* out = (float*)d_out;

    char* ws = (char*)d_ws;
    u16* state_g = (u16*)(ws + WS_STATE);
    u16* fW1b = (u16*)(ws + WS_FW1);
    u16* fW2b = (u16*)(ws + WS_FW2);
    u16* pWb  = (u16*)(ws + WS_PW);
    u16* tWb  = (u16*)(ws + WS_TW);
    u16* oW1b = (u16*)(ws + WS_OW1);
    u16* oW2b = (u16*)(ws + WS_OW2);
    int* cnt  = (int*)(ws + WS_CNT);
    int* idx  = (int*)(ws + WS_IDX);

    hipMemsetAsync(cnt, 0, N_OPT * sizeof(int), stream);
    k_prep<<<64, 256, 0, stream>>>(fW1, fW2, pW, tW, oW1, oW2,
                                   fW1b, fW2b, pWb, tWb, oW1b, oW2b);
    k_bucket<<<BATCH / 256, 256, 0, stream>>>(opt, cnt, idx);
    k_trunk<<<BATCH / 64, 256, 0, stream>>>(obs, opt, fW1b, fb1, fW2b, fb2,
                                            pWb, pb, tWb, tb, state_g, out);
    k_expert<<<512, 256, 0, stream>>>(state_g, cnt, idx, act,
                                      oW1b, ob1, oW2b, ob2, out);
}